// Round 12
// baseline (112.636 us; speedup 1.0000x reference)
//
#include <hip/hip_runtime.h>

#define N_NODES 100000
#define N_EDGES 1600000
#define D_IN    256
#define D_OUT   128

typedef __attribute__((ext_vector_type(8))) short          bf16x8;
typedef __attribute__((ext_vector_type(8))) unsigned short ushort8;
typedef __attribute__((ext_vector_type(4))) float          f32x4;

// f32 -> bf16 (round-to-nearest-even), as raw ushort
__device__ inline unsigned short f2bf(float f) {
  union { float f; unsigned u; } v; v.f = f;
  unsigned r = v.u + 0x7fffu + ((v.u >> 16) & 1u);
  return (unsigned short)(r >> 16);
}
__device__ inline float bf2f(unsigned short u) {
  union { unsigned u; float f; } v; v.u = ((unsigned)u) << 16;
  return v.f;
}

// ---------------------------------------------------------------------------
// Kernel 0 (merged): [threads 0..4095] pack W f32 -> bf16 MFMA B-fragment
// order (frag f = (n*8+s)*64+lane holds W[col=n*16+(lane&15)][k=s*32+(lane>>4)*8+j],
// layout verified rounds 4-11); [threads 4096..] row_ptr[v] = lower_bound(dst,v).
// ---------------------------------------------------------------------------
__global__ __launch_bounds__(256) void gcn_prep_kernel(
    const float* __restrict__ W, unsigned short* __restrict__ Wp,
    const int* __restrict__ dst, int* __restrict__ row_ptr) {
  int gid = blockIdx.x * blockDim.x + threadIdx.x;
  if (gid < 4096) {
    int f = gid;
    int n = f >> 9, s = (f >> 6) & 7, lane = f & 63;
    int col = n * 16 + (lane & 15);
    int k0  = s * 32 + (lane >> 4) * 8;
#pragma unroll
    for (int j = 0; j < 8; ++j)
      Wp[f * 8 + j] = f2bf(W[col * D_IN + k0 + j]);
  } else {
    int v = gid - 4096;
    if (v > N_NODES) return;
    int lo = 0, hi = N_EDGES;
    while (lo < hi) {
      int mid = (lo + hi) >> 1;
      if (dst[mid] < v) lo = mid + 1; else hi = mid;
    }
    row_ptr[v] = lo;
  }
}

// ---------------------------------------------------------------------------
// Kernel 1: h[N][128] (bf16) = bf16(x) @ W^T + b via mfma_f32_16x16x32_bf16.
// 1024-THREAD BLOCK = 16 waves sharing ONE 64 KB W-pack staging:
//   waves 0-7  -> rows (wid&7)*16, cols 0..63
//   waves 8-15 -> same rows,       cols 64..127
// This combines what rounds 8 and 11 each got only half of:
//   - x traffic stays 102 MB chip-wide (round 11's col-split doubled it:
//     both halves of a row stripe are read in the SAME block, concurrently,
//     so the second read hits L1/L2);
//   - per-wave acc is 4 fragments = 16 VGPR -> launch_bounds(1024,8) holds
//     <=64 VGPR -> 8 waves/SIMD; LDS 64 KB x 2 blocks/CU = 2048 thr/CU
//     = 100% occupancy (round 8 was capped at 50% by 96 VGPR + 64 KB LDS).
// A layout: lane holds A[row=lane&15][k=(lane>>4)*8 + j].
// C layout: lane holds D[row=(lane>>4)*4 + i][col=lane&15].
// ---------------------------------------------------------------------------
__global__ __launch_bounds__(1024, 8) void gcn_linear_mfma_kernel(
    const float* __restrict__ x, const unsigned short* __restrict__ Wp,
    const float* __restrict__ b, unsigned short* __restrict__ h) {
  __shared__ unsigned short lW[32768];   // 64 KiB, full fragment-ordered pack
  const int tid  = threadIdx.x;
  const int lane = tid & 63;
  const int wid  = tid >> 6;             // 0..15
  const int half = wid >> 3;             // 0: cols 0..63, 1: cols 64..127
  const int r0   = blockIdx.x * 128 + (wid & 7) * 16;

  // stage full W-pack: 4096 frags x 16 B, 1024 threads -> 4 iters, coalesced
#pragma unroll
  for (int i = 0; i < 4; ++i) {
    int idx = i * 1024 + tid;
    *(ushort8*)(&lW[idx * 8]) = *(const ushort8*)(Wp + (size_t)idx * 8);
  }
  __syncthreads();

  int arow = r0 + (lane & 15);
  arow = arow < N_NODES ? arow : N_NODES - 1;      // clamp; OOB rows never stored
  const int kg = (lane >> 4) * 8;
  const float* xrow = x + (size_t)arow * D_IN + kg;

  f32x4 acc[4];
#pragma unroll
  for (int n = 0; n < 4; ++n) acc[n] = (f32x4){0.f, 0.f, 0.f, 0.f};

#pragma unroll
  for (int s = 0; s < 8; ++s) {
    float4 a0 = *(const float4*)(xrow + s * 32);
    float4 a1 = *(const float4*)(xrow + s * 32 + 4);
    bf16x8 af;
    af[0] = (short)f2bf(a0.x); af[1] = (short)f2bf(a0.y);
    af[2] = (short)f2bf(a0.z); af[3] = (short)f2bf(a0.w);
    af[4] = (short)f2bf(a1.x); af[5] = (short)f2bf(a1.y);
    af[6] = (short)f2bf(a1.z); af[7] = (short)f2bf(a1.w);
#pragma unroll
    for (int n = 0; n < 4; ++n) {
      const int n2 = half * 4 + n;       // global col-fragment 0..7
      bf16x8 bfrag = *(const bf16x8*)(&lW[(size_t)((n2 * 8 + s) * 64 + lane) * 8]);
      acc[n] = __builtin_amdgcn_mfma_f32_16x16x32_bf16(af, bfrag, acc[n], 0, 0, 0);
    }
  }

  // epilogue: + bias, bf16 store (scalar 2B stores; 16-lane col groups
  // coalesce to 32B segments — WRITE_SIZE confirmed efficient rounds 4-8)
  const int col0 = lane & 15;
  const int q4   = (lane >> 4) * 4;
#pragma unroll
  for (int n = 0; n < 4; ++n) {
    const int col = half * 64 + n * 16 + col0;
    const float bias = b[col];
#pragma unroll
    for (int i = 0; i < 4; ++i) {
      const int row = r0 + q4 + i;
      if (row < N_NODES)
        h[(size_t)row * D_OUT + col] = f2bf(acc[n][i] + bias);
    }
  }
}

// ---------------------------------------------------------------------------
// Kernel 2 (round-8 structure, measured optimum — rounds 7/9 proved finer
// chunkings regress): one WAVE per node, 4 lane-groups x 16 lanes, 4 edges
// per group per iteration (16 edges/wave = mean degree). Per-edge gather =
// FULL 256 B row (2 complete cache lines, zero fill waste). shfl_xor(16,32)
// cross-group reduce, float4 store. Atomic-free, deterministic.
// Structural wall: 410 MB gather demand, FETCH ~185 MB ~= 8 XCDs x 25.6 MB
// (each L2 pulls h once) -> ~67 us at the mixed L2/L3/HBM service rate.
// ---------------------------------------------------------------------------
__global__ __launch_bounds__(256) void gcn_agg_kernel(
    const unsigned short* __restrict__ h, const int* __restrict__ src,
    const float* __restrict__ w, const int* __restrict__ rp,
    float* __restrict__ out) {
  const int node = (blockIdx.x << 2) + (threadIdx.x >> 6);
  if (node >= N_NODES) return;
  const int lane = threadIdx.x & 63;
  const int g  = lane >> 4;          // group 0..3
  const int dg = (lane & 15) << 3;   // dim offset 0,8,...,120

  const int s = rp[node], e = rp[node + 1];
  float acc[8];
#pragma unroll
  for (int j = 0; j < 8; ++j) acc[j] = 0.f;

  for (int base = s; base < e; base += 16) {
    const int i0 = base + (g << 2);      // group-uniform
    if (i0 < e) {
      int   sv[4];
      float wv[4];
#pragma unroll
      for (int j = 0; j < 4; ++j) {
        int  i = i0 + j;
        bool valid = (i < e);
        int  ic = valid ? i : i0;        // i0 is valid here
        sv[j] = src[ic];
        wv[j] = valid ? w[ic] : 0.f;
      }
      ushort8 hv[4];
#pragma unroll
      for (int j = 0; j < 4; ++j)
        hv[j] = *(const ushort8*)(h + (size_t)sv[j] * D_OUT + dg);
#pragma unroll
      for (int j = 0; j < 4; ++j)
#pragma unroll
        for (int k = 0; k < 8; ++k)
          acc[k] += bf2f(hv[j][k]) * wv[j];
    }
  }

#pragma unroll
  for (int j = 0; j < 8; ++j) acc[j] += __shfl_xor(acc[j], 16);
#pragma unroll
  for (int j = 0; j < 8; ++j) acc[j] += __shfl_xor(acc[j], 32);

  if (g == 0) {
    float4 o0 = {acc[0], acc[1], acc[2], acc[3]};
    float4 o1 = {acc[4], acc[5], acc[6], acc[7]};
    float* op = out + (size_t)node * D_OUT + dg;
    *(float4*)(op)     = o0;
    *(float4*)(op + 4) = o1;
  }
}

extern "C" void kernel_launch(void* const* d_in, const int* in_sizes, int n_in,
                              void* d_out, int out_size, void* d_ws, size_t ws_size,
                              hipStream_t stream) {
  const float* x   = (const float*)d_in[0];
  const int*   src = (const int*)d_in[1];
  const int*   dst = (const int*)d_in[2];
  const float* w   = (const float*)d_in[3];
  const float* W   = (const float*)d_in[4];
  const float* b   = (const float*)d_in[5];
  float* out = (float*)d_out;

  // workspace: Wpack (64 KB) | h bf16 [N][128] (25.6 MB) | row_ptr (400 KB)
  unsigned short* Wp = (unsigned short*)d_ws;
  unsigned short* h  = (unsigned short*)((char*)d_ws + 65536);
  int* row_ptr = (int*)((char*)d_ws + 65536 + (size_t)N_NODES * D_OUT * sizeof(unsigned short));

  // 0) pack W + CSR offsets (merged, independent of h)
  gcn_prep_kernel<<<(4096 + N_NODES + 1 + 255) / 256, 256, 0, stream>>>(W, Wp, dst, row_ptr);
  // 1) h = bf16(x @ W^T + b): 128 rows x 128 cols per 1024-thread block
  gcn_linear_mfma_kernel<<<(N_NODES + 127) / 128, 1024, 0, stream>>>(x, Wp, b, h);
  // 2) segment-sum of w-scaled gathered rows (round-8 structure)
  gcn_agg_kernel<<<N_NODES / 4, 256, 0, stream>>>(h, src, w, row_ptr, out);
}

// Round 13
// 101.954 us; speedup vs baseline: 1.1048x; 1.1048x over previous
//
#include <hip/hip_runtime.h>

#define N_NODES 100000
#define N_EDGES 1600000
#define D_IN    256
#define D_OUT   128

// rowptr: 100001 entries at 512 thr/block
#define RP_BLOCKS ((N_NODES + 1 + 511) / 512)
#define LIN_BLOCKS ((N_NODES + 127) / 128)

typedef __attribute__((ext_vector_type(8))) short          bf16x8;
typedef __attribute__((ext_vector_type(8))) unsigned short ushort8;
typedef __attribute__((ext_vector_type(4))) float          f32x4;

// f32 -> bf16 (round-to-nearest-even), as raw ushort
__device__ inline unsigned short f2bf(float f) {
  union { float f; unsigned u; } v; v.f = f;
  unsigned r = v.u + 0x7fffu + ((v.u >> 16) & 1u);
  return (unsigned short)(r >> 16);
}
__device__ inline float bf2f(unsigned short u) {
  union { unsigned u; float f; } v; v.u = ((unsigned)u) << 16;
  return v.f;
}

// ---------------------------------------------------------------------------
// Kernel 0: pack W[D_OUT][D_IN] f32 -> bf16 MFMA B-fragment order.
// Frag f = (n*8 + s)*64 + lane holds B[k = s*32+(lane>>4)*8 + j][col = n*16+(lane&15)]
//        = W[col][k], j = 0..7.  (Layout verified rounds 4-12.)  ~2 us.
// ---------------------------------------------------------------------------
__global__ __launch_bounds__(256) void gcn_packW_kernel(
    const float* __restrict__ W, unsigned short* __restrict__ Wp) {
  int f = blockIdx.x * blockDim.x + threadIdx.x;   // 0..4095
  if (f >= 4096) return;
  int n = f >> 9, s = (f >> 6) & 7, lane = f & 63;
  int col = n * 16 + (lane & 15);
  int k0  = s * 32 + (lane >> 4) * 8;
#pragma unroll
  for (int j = 0; j < 8; ++j)
    Wp[f * 8 + j] = f2bf(W[col * D_IN + k0 + j]);
}

// ---------------------------------------------------------------------------
// Kernel 1 (merged): blocks [0, RP_BLOCKS) compute row_ptr via binary search
// over the sorted dst (latency-bound, ~3-4 us) — hidden in the shadow of the
// memory-bound linear blocks [RP_BLOCKS, RP_BLOCKS+LIN_BLOCKS), which are the
// round-8-proven structure: 512 thr = 8 waves x 16 rows = 128 rows/block,
// full 64 KB W-pack staged in LDS (B-operand chain = ds_read_b128), VMEM
// carries only the coalesced x stream.
// Linear is invariant at ~40 us across occupancy 50->100% and 2x traffic
// (rounds 8/10/11/12) -> pinned at the ~3.2 TB/s beyond-L2 service rate,
// matching agg's 3.6 -> structural, not schedulable away.
// A layout: lane holds A[row=lane&15][k=(lane>>4)*8 + j].
// C layout: lane holds D[row=(lane>>4)*4 + i][col=lane&15].
// ---------------------------------------------------------------------------
__global__ __launch_bounds__(512) void gcn_linear_rowptr_kernel(
    const float* __restrict__ x, const unsigned short* __restrict__ Wp,
    const float* __restrict__ b, unsigned short* __restrict__ h,
    const int* __restrict__ dst, int* __restrict__ row_ptr) {
  __shared__ unsigned short lW[32768];   // 64 KiB, fragment-ordered
  const int tid = threadIdx.x;

  if (blockIdx.x < RP_BLOCKS) {
    // ---- rowptr branch: row_ptr[v] = lower_bound(dst, v) ----
    int v = blockIdx.x * 512 + tid;
    if (v > N_NODES) return;
    int lo = 0, hi = N_EDGES;
    while (lo < hi) {
      int mid = (lo + hi) >> 1;
      if (dst[mid] < v) lo = mid + 1; else hi = mid;
    }
    row_ptr[v] = lo;
    return;
  }

  // ---- linear branch (round-8 structure) ----
  const int lbid = blockIdx.x - RP_BLOCKS;
  const int lane = tid & 63;
  const int wid  = tid >> 6;             // 0..7
  const int r0   = lbid * 128 + wid * 16;

  // stage W-pack: 4096 x 16 B, 512 threads -> 8 iters, fully coalesced
#pragma unroll
  for (int i = 0; i < 8; ++i) {
    int idx = i * 512 + tid;
    *(ushort8*)(&lW[idx * 8]) = *(const ushort8*)(Wp + (size_t)idx * 8);
  }
  __syncthreads();

  int arow = r0 + (lane & 15);
  arow = arow < N_NODES ? arow : N_NODES - 1;      // clamp; OOB rows never stored
  const int kg = (lane >> 4) * 8;
  const float* xrow = x + (size_t)arow * D_IN + kg;

  f32x4 acc[8];
#pragma unroll
  for (int n = 0; n < 8; ++n) acc[n] = (f32x4){0.f, 0.f, 0.f, 0.f};

#pragma unroll
  for (int s = 0; s < 8; ++s) {
    float4 a0 = *(const float4*)(xrow + s * 32);
    float4 a1 = *(const float4*)(xrow + s * 32 + 4);
    bf16x8 af;
    af[0] = (short)f2bf(a0.x); af[1] = (short)f2bf(a0.y);
    af[2] = (short)f2bf(a0.z); af[3] = (short)f2bf(a0.w);
    af[4] = (short)f2bf(a1.x); af[5] = (short)f2bf(a1.y);
    af[6] = (short)f2bf(a1.z); af[7] = (short)f2bf(a1.w);
#pragma unroll
    for (int n = 0; n < 8; ++n) {
      bf16x8 bfrag = *(const bf16x8*)(&lW[(size_t)((n * 8 + s) * 64 + lane) * 8]);
      acc[n] = __builtin_amdgcn_mfma_f32_16x16x32_bf16(af, bfrag, acc[n], 0, 0, 0);
    }
  }

  // epilogue: + bias, bf16 store (scalar 2B stores, 16-lane col groups
  // coalesce to 32B segments; WRITE_SIZE confirmed efficient rounds 4-8)
  const int col0 = lane & 15;
  const int q4   = (lane >> 4) * 4;
#pragma unroll
  for (int n = 0; n < 8; ++n) {
    const int col = n * 16 + col0;
    const float bias = b[col];
#pragma unroll
    for (int i = 0; i < 4; ++i) {
      const int row = r0 + q4 + i;
      if (row < N_NODES)
        h[(size_t)row * D_OUT + col] = f2bf(acc[n][i] + bias);
    }
  }
}

// ---------------------------------------------------------------------------
// Kernel 2 (round-8 structure, measured optimum — rounds 7/9 proved finer
// chunkings regress): one WAVE per node, 4 lane-groups x 16 lanes, 4 edges
// per group per iteration (16 edges/wave = mean degree). Per-edge gather =
// FULL 256 B row (2 complete cache lines, zero fill waste). shfl_xor(16,32)
// cross-group reduce, float4 store. Atomic-free, deterministic.
// Structural wall: 410 MB gather demand, FETCH ~185 MB ~= 8 XCDs x 25.6 MB
// (each L2 pulls h once) -> ~67 us at the ~3.6 TB/s beyond-L2 service rate.
// ---------------------------------------------------------------------------
__global__ __launch_bounds__(256) void gcn_agg_kernel(
    const unsigned short* __restrict__ h, const int* __restrict__ src,
    const float* __restrict__ w, const int* __restrict__ rp,
    float* __restrict__ out) {
  const int node = (blockIdx.x << 2) + (threadIdx.x >> 6);
  if (node >= N_NODES) return;
  const int lane = threadIdx.x & 63;
  const int g  = lane >> 4;          // group 0..3
  const int dg = (lane & 15) << 3;   // dim offset 0,8,...,120

  const int s = rp[node], e = rp[node + 1];
  float acc[8];
#pragma unroll
  for (int j = 0; j < 8; ++j) acc[j] = 0.f;

  for (int base = s; base < e; base += 16) {
    const int i0 = base + (g << 2);      // group-uniform
    if (i0 < e) {
      int   sv[4];
      float wv[4];
#pragma unroll
      for (int j = 0; j < 4; ++j) {
        int  i = i0 + j;
        bool valid = (i < e);
        int  ic = valid ? i : i0;        // i0 is valid here
        sv[j] = src[ic];
        wv[j] = valid ? w[ic] : 0.f;
      }
      ushort8 hv[4];
#pragma unroll
      for (int j = 0; j < 4; ++j)
        hv[j] = *(const ushort8*)(h + (size_t)sv[j] * D_OUT + dg);
#pragma unroll
      for (int j = 0; j < 4; ++j)
#pragma unroll
        for (int k = 0; k < 8; ++k)
          acc[k] += bf2f(hv[j][k]) * wv[j];
    }
  }

#pragma unroll
  for (int j = 0; j < 8; ++j) acc[j] += __shfl_xor(acc[j], 16);
#pragma unroll
  for (int j = 0; j < 8; ++j) acc[j] += __shfl_xor(acc[j], 32);

  if (g == 0) {
    float4 o0 = {acc[0], acc[1], acc[2], acc[3]};
    float4 o1 = {acc[4], acc[5], acc[6], acc[7]};
    float* op = out + (size_t)node * D_OUT + dg;
    *(float4*)(op)     = o0;
    *(float4*)(op + 4) = o1;
  }
}

extern "C" void kernel_launch(void* const* d_in, const int* in_sizes, int n_in,
                              void* d_out, int out_size, void* d_ws, size_t ws_size,
                              hipStream_t stream) {
  const float* x   = (const float*)d_in[0];
  const int*   src = (const int*)d_in[1];
  const int*   dst = (const int*)d_in[2];
  const float* w   = (const float*)d_in[3];
  const float* W   = (const float*)d_in[4];
  const float* b   = (const float*)d_in[5];
  float* out = (float*)d_out;

  // workspace: Wpack (64 KB) | h bf16 [N][128] (25.6 MB) | row_ptr (400 KB)
  unsigned short* Wp = (unsigned short*)d_ws;
  unsigned short* h  = (unsigned short*)((char*)d_ws + 65536);
  int* row_ptr = (int*)((char*)d_ws + 65536 + (size_t)N_NODES * D_OUT * sizeof(unsigned short));

  // 0) pack W -> bf16 fragment order (~2 us)
  gcn_packW_kernel<<<16, 256, 0, stream>>>(W, Wp);
  // 1) merged: rowptr (196 blocks, hidden) + linear (782 blocks, round-8)
  gcn_linear_rowptr_kernel<<<RP_BLOCKS + LIN_BLOCKS, 512, 0, stream>>>(
      x, Wp, b, h, dst, row_ptr);
  // 2) segment-sum of w-scaled gathered rows (round-8 structure)
  gcn_agg_kernel<<<N_NODES / 4, 256, 0, stream>>>(h, src, w, row_ptr, out);
}